// Round 1
// baseline (133.594 us; speedup 1.0000x reference)
//
#include <hip/hip_runtime.h>
#include <math.h>

#define H 4096
#define H4 (H / 4)          // columns as float4
constexpr int ROWS = 64;    // rows per chunk per block

struct Job { const float* W; const float* v; float* a; };
struct Jobs { Job j[4]; };

// Zero the 4 accumulators (4*H floats at start of ws)
__global__ __launch_bounds__(256) void zero_acc(float* __restrict__ ws) {
    int i = blockIdx.x * 256 + threadIdx.x;
    ws[i] = 0.0f;
}

// Generic chunked matvec: acc[j] += sum_i v[i] * W[i*H + j]
// grid = (H4/256 = 4 col-blocks, H/ROWS row-chunks, n_jobs)
__global__ __launch_bounds__(256) void matvec_multi(Jobs jobs) {
    const Job jb = jobs.j[blockIdx.z];
    const int c4 = blockIdx.x * 256 + threadIdx.x;     // float4 column index
    const int row0 = blockIdx.y * ROWS;

    const float4* __restrict__ Wv =
        reinterpret_cast<const float4*>(jb.W) + (size_t)row0 * H4 + c4;
    const float* __restrict__ v = jb.v + row0;

    float4 s = {0.f, 0.f, 0.f, 0.f};
#pragma unroll 8
    for (int i = 0; i < ROWS; ++i) {
        const float xv = v[i];                          // uniform -> scalar load
        const float4 w = Wv[(size_t)i * H4];
        s.x = fmaf(xv, w.x, s.x);
        s.y = fmaf(xv, w.y, s.y);
        s.z = fmaf(xv, w.z, s.z);
        s.w = fmaf(xv, w.w, s.w);
    }
    float* a = jb.a + 4 * c4;
    atomicAdd(a + 0, s.x);
    atomicAdd(a + 1, s.y);
    atomicAdd(a + 2, s.z);
    atomicAdd(a + 3, s.w);
}

// m = accM + b_m ; x_tilde = x * m
__global__ __launch_bounds__(256) void finA(const float* __restrict__ accM,
                                            const float* __restrict__ b_m,
                                            const float* __restrict__ x,
                                            float* __restrict__ x_tilde) {
    int i = blockIdx.x * 256 + threadIdx.x;
    float m = accM[i] + b_m[i];
    x_tilde[i] = x[i] * m;
}

// z = sigmoid(accZ + b_z); r = sigmoid(accR + b_r); rh = r * h
__global__ __launch_bounds__(256) void finB(const float* __restrict__ accZ,
                                            const float* __restrict__ accR,
                                            const float* __restrict__ b_z,
                                            const float* __restrict__ b_r,
                                            const float* __restrict__ h,
                                            float* __restrict__ z_out,
                                            float* __restrict__ rh) {
    int i = blockIdx.x * 256 + threadIdx.x;
    float z = 1.0f / (1.0f + expf(-(accZ[i] + b_z[i])));
    float r = 1.0f / (1.0f + expf(-(accR[i] + b_r[i])));
    z_out[i] = z;
    rh[i] = r * h[i];
}

// h_t = (1-z)*h + z*tanh(accH + b_h)
__global__ __launch_bounds__(256) void finC(const float* __restrict__ accH,
                                            const float* __restrict__ b_h,
                                            const float* __restrict__ z,
                                            const float* __restrict__ h,
                                            float* __restrict__ out) {
    int i = blockIdx.x * 256 + threadIdx.x;
    float ht = tanhf(accH[i] + b_h[i]);
    float zz = z[i];
    out[i] = (1.0f - zz) * h[i] + zz * ht;
}

extern "C" void kernel_launch(void* const* d_in, const int* in_sizes, int n_in,
                              void* d_out, int out_size, void* d_ws, size_t ws_size,
                              hipStream_t stream) {
    const float* x   = (const float*)d_in[0];
    const float* h   = (const float*)d_in[1];
    const float* W_m = (const float*)d_in[2];
    const float* W_z = (const float*)d_in[3];
    const float* W_r = (const float*)d_in[4];
    const float* W_h = (const float*)d_in[5];
    const float* U_m = (const float*)d_in[6];
    const float* U_z = (const float*)d_in[7];
    const float* U_r = (const float*)d_in[8];
    const float* U_h = (const float*)d_in[9];
    const float* b_m = (const float*)d_in[10];
    const float* b_z = (const float*)d_in[11];
    const float* b_r = (const float*)d_in[12];
    const float* b_h = (const float*)d_in[13];
    float* out = (float*)d_out;

    float* ws      = (float*)d_ws;
    float* accM    = ws + 0 * H;
    float* accZ    = ws + 1 * H;
    float* accR    = ws + 2 * H;
    float* accH    = ws + 3 * H;
    float* x_tilde = ws + 4 * H;
    float* rh      = ws + 5 * H;
    float* zbuf    = ws + 6 * H;

    // 1. zero the 4 accumulators
    zero_acc<<<(4 * H) / 256, 256, 0, stream>>>(ws);

    // 2. Phase A: x@W_m, h@U_m -> accM ; h@U_z -> accZ ; h@U_r -> accR
    Jobs ja;
    ja.j[0] = {W_m, x, accM};
    ja.j[1] = {U_m, h, accM};
    ja.j[2] = {U_z, h, accZ};
    ja.j[3] = {U_r, h, accR};
    matvec_multi<<<dim3(H4 / 256, H / ROWS, 4), 256, 0, stream>>>(ja);

    // 3. x_tilde = x * (accM + b_m)
    finA<<<H / 256, 256, 0, stream>>>(accM, b_m, x, x_tilde);

    // 4. Phase B: x_tilde@W_z -> accZ ; x_tilde@W_r -> accR
    Jobs jb;
    jb.j[0] = {W_z, x_tilde, accZ};
    jb.j[1] = {W_r, x_tilde, accR};
    jb.j[2] = jb.j[0];
    jb.j[3] = jb.j[0];
    matvec_multi<<<dim3(H4 / 256, H / ROWS, 2), 256, 0, stream>>>(jb);

    // 5. z, r, rh
    finB<<<H / 256, 256, 0, stream>>>(accZ, accR, b_z, b_r, h, zbuf, rh);

    // 6. Phase C: x_tilde@W_h -> accH ; rh@U_h -> accH
    Jobs jc;
    jc.j[0] = {W_h, x_tilde, accH};
    jc.j[1] = {U_h, rh, accH};
    jc.j[2] = jc.j[0];
    jc.j[3] = jc.j[0];
    matvec_multi<<<dim3(H4 / 256, H / ROWS, 2), 256, 0, stream>>>(jc);

    // 7. output
    finC<<<H / 256, 256, 0, stream>>>(accH, b_h, zbuf, h, out);
}